// Round 1
// baseline (1355.822 us; speedup 1.0000x reference)
//
#include <hip/hip_runtime.h>
#include <hip/hip_bf16.h>
#include <math.h>

#define D_MODEL 1024
#define NH      16
#define DK      64
#define S_LEN   2048
#define BATCH   2
#define M_ROWS  (BATCH * S_LEN)   // 4096

// ---------------------------------------------------------------------------
// Projection / output GEMM:  Y[m][n] = sum_k X[m][k] * W[n][k] + bias[n]
// (torch Linear: y = x @ W.T + b; both X and W are K-contiguous row-major)
// BM=BN=64, BK=16, 256 threads, 4x4 microtile per thread.
// HEAD_SPLIT: write Y into [B, H, S, DK] layout instead of [M, N].
// ---------------------------------------------------------------------------
template <bool HEAD_SPLIT>
__global__ __launch_bounds__(256) void proj_gemm(const float* __restrict__ X,
                                                 const float* __restrict__ W,
                                                 const float* __restrict__ bias,
                                                 float* __restrict__ Y) {
    __shared__ float As[16][68];  // [k][m], padded row to 68 floats (16B-aligned rows)
    __shared__ float Bs[16][68];  // [k][n]

    const int tid = threadIdx.x;
    const int m0 = blockIdx.y * 64;
    const int n0 = blockIdx.x * 64;
    const int tx = tid & 15;   // n direction
    const int ty = tid >> 4;   // m direction

    // cooperative-load mapping: each thread loads one float4 of A and of B
    const int lr = tid >> 2;         // 0..63: row within tile
    const int lc = (tid & 3) * 4;    // 0,4,8,12: k within tile

    float acc[4][4];
#pragma unroll
    for (int i = 0; i < 4; ++i)
#pragma unroll
        for (int j = 0; j < 4; ++j) acc[i][j] = 0.f;

    for (int k0 = 0; k0 < D_MODEL; k0 += 16) {
        const float4 av = *(const float4*)&X[(size_t)(m0 + lr) * D_MODEL + k0 + lc];
        const float4 bv = *(const float4*)&W[(size_t)(n0 + lr) * D_MODEL + k0 + lc];
        __syncthreads();  // previous iteration's reads done before overwrite
        As[lc + 0][lr] = av.x; As[lc + 1][lr] = av.y;
        As[lc + 2][lr] = av.z; As[lc + 3][lr] = av.w;
        Bs[lc + 0][lr] = bv.x; Bs[lc + 1][lr] = bv.y;
        Bs[lc + 2][lr] = bv.z; Bs[lc + 3][lr] = bv.w;
        __syncthreads();
#pragma unroll
        for (int k = 0; k < 16; ++k) {
            const float4 a = *(const float4*)&As[k][ty * 4];
            const float4 b = *(const float4*)&Bs[k][tx * 4];
            const float aa[4] = {a.x, a.y, a.z, a.w};
            const float bb[4] = {b.x, b.y, b.z, b.w};
#pragma unroll
            for (int i = 0; i < 4; ++i)
#pragma unroll
                for (int j = 0; j < 4; ++j) acc[i][j] = fmaf(aa[i], bb[j], acc[i][j]);
        }
    }

#pragma unroll
    for (int i = 0; i < 4; ++i) {
        const int m = m0 + ty * 4 + i;
#pragma unroll
        for (int j = 0; j < 4; ++j) {
            const int n = n0 + tx * 4 + j;
            const float v = acc[i][j] + bias[n];
            if (HEAD_SPLIT) {
                const int b = m >> 11;          // m / S_LEN
                const int s = m & (S_LEN - 1);
                const int h = n >> 6;           // n / DK
                const int d = n & (DK - 1);
                Y[((((size_t)b * NH + h) * S_LEN) + s) * DK + d] = v;
            } else {
                Y[(size_t)m * D_MODEL + n] = v;
            }
        }
    }
}

// ---------------------------------------------------------------------------
// Flash attention (fp32): one block per (b, h, 64-row q tile).
// 256 threads = 64 q-rows x 4 lanes; each lane owns 16 of the 64 dk dims.
// K/V tiles (64x64) staged in LDS; online softmax state in registers.
// Output written in [B, S, D_MODEL] layout (ready for the output GEMM).
// ---------------------------------------------------------------------------
__global__ __launch_bounds__(256) void flash_attn(const float* __restrict__ q,
                                                  const float* __restrict__ k,
                                                  const float* __restrict__ v,
                                                  float* __restrict__ out) {
    __shared__ float Ks[64][68];
    __shared__ float Vs[64][68];

    const int tid  = threadIdx.x;
    const int row  = tid >> 2;          // 0..63: q row within tile
    const int doff = (tid & 3) * 16;    // this lane's dk slice
    const int qt = blockIdx.x;          // q tile index, 0..31
    const int h  = blockIdx.y;
    const int b  = blockIdx.z;
    const int bh = b * NH + h;
    const int qrow = qt * 64 + row;     // global q row within sequence

    // load this row's Q slice (16 floats) into registers
    float qreg[16];
    {
        const float* qp = &q[(((size_t)bh * S_LEN) + qrow) * DK + doff];
#pragma unroll
        for (int j = 0; j < 4; ++j) {
            const float4 t = *(const float4*)&qp[j * 4];
            qreg[j * 4 + 0] = t.x; qreg[j * 4 + 1] = t.y;
            qreg[j * 4 + 2] = t.z; qreg[j * 4 + 3] = t.w;
        }
    }

    float m_run = -INFINITY;
    float l_run = 0.f;
    float o_acc[16];
#pragma unroll
    for (int j = 0; j < 16; ++j) o_acc[j] = 0.f;

    const float scale = 0.125f;  // 1/sqrt(64)

    for (int kt = 0; kt < S_LEN / 64; ++kt) {
        __syncthreads();  // previous tile's reads done
        // stage K and V tiles: 64x64 floats each, one float4 x4 per thread
#pragma unroll
        for (int j = 0; j < 4; ++j) {
            const int linear = tid + j * 256;       // 0..1023 float4 slots
            const int r  = linear >> 4;             // 0..63
            const int c4 = (linear & 15) * 4;       // 0..60
            const size_t g = (((size_t)bh * S_LEN) + kt * 64 + r) * DK + c4;
            *(float4*)&Ks[r][c4] = *(const float4*)&k[g];
            *(float4*)&Vs[r][c4] = *(const float4*)&v[g];
        }
        __syncthreads();

        // scores for this row vs 64 keys
        float s_arr[64];
#pragma unroll
        for (int kk = 0; kk < 64; ++kk) {
            float p = 0.f;
#pragma unroll
            for (int j = 0; j < 4; ++j) {
                const float4 t = *(const float4*)&Ks[kk][doff + j * 4];
                p = fmaf(qreg[j * 4 + 0], t.x, p);
                p = fmaf(qreg[j * 4 + 1], t.y, p);
                p = fmaf(qreg[j * 4 + 2], t.z, p);
                p = fmaf(qreg[j * 4 + 3], t.w, p);
            }
            p += __shfl_xor(p, 1);
            p += __shfl_xor(p, 2);
            s_arr[kk] = p * scale;
        }

        // online softmax update
        float tmax = s_arr[0];
#pragma unroll
        for (int kk = 1; kk < 64; ++kk) tmax = fmaxf(tmax, s_arr[kk]);
        const float m_new = fmaxf(m_run, tmax);
        const float fac = __expf(m_run - m_new);  // 0 on first tile (m_run=-inf)
        l_run *= fac;
#pragma unroll
        for (int j = 0; j < 16; ++j) o_acc[j] *= fac;
#pragma unroll
        for (int kk = 0; kk < 64; ++kk) {
            const float p = __expf(s_arr[kk] - m_new);
            l_run += p;
#pragma unroll
            for (int j = 0; j < 4; ++j) {
                const float4 t = *(const float4*)&Vs[kk][doff + j * 4];
                o_acc[j * 4 + 0] = fmaf(p, t.x, o_acc[j * 4 + 0]);
                o_acc[j * 4 + 1] = fmaf(p, t.y, o_acc[j * 4 + 1]);
                o_acc[j * 4 + 2] = fmaf(p, t.z, o_acc[j * 4 + 2]);
                o_acc[j * 4 + 3] = fmaf(p, t.w, o_acc[j * 4 + 3]);
            }
        }
        m_run = m_new;
    }

    const float inv_l = 1.f / l_run;
    // write to [B, S, D_MODEL]: row (b*S + qrow), col (h*DK + doff + j)
    float* op = &out[(((size_t)b * S_LEN) + qrow) * D_MODEL + h * DK + doff];
#pragma unroll
    for (int j = 0; j < 4; ++j) {
        float4 t;
        t.x = o_acc[j * 4 + 0] * inv_l; t.y = o_acc[j * 4 + 1] * inv_l;
        t.z = o_acc[j * 4 + 2] * inv_l; t.w = o_acc[j * 4 + 3] * inv_l;
        *(float4*)&op[j * 4] = t;
    }
}

// ---------------------------------------------------------------------------
extern "C" void kernel_launch(void* const* d_in, const int* in_sizes, int n_in,
                              void* d_out, int out_size, void* d_ws, size_t ws_size,
                              hipStream_t stream) {
    const float* Q  = (const float*)d_in[0];
    const float* K  = (const float*)d_in[1];
    const float* V  = (const float*)d_in[2];
    const float* Wq = (const float*)d_in[3];
    const float* bq = (const float*)d_in[4];
    const float* Wk = (const float*)d_in[5];
    const float* bk = (const float*)d_in[6];
    const float* Wv = (const float*)d_in[7];
    const float* bv = (const float*)d_in[8];
    const float* Wo = (const float*)d_in[9];
    const float* bo = (const float*)d_in[10];
    float* out = (float*)d_out;

    const size_t elems = (size_t)BATCH * NH * S_LEN * DK;  // 4,194,304
    float* qws = (float*)d_ws;
    float* kws = qws + elems;
    float* vws = kws + elems;
    float* aws = vws + elems;   // [B, S, D_MODEL]

    const dim3 gemm_grid(D_MODEL / 64, M_ROWS / 64);  // (16, 64)
    proj_gemm<true><<<gemm_grid, 256, 0, stream>>>(Q, Wq, bq, qws);
    proj_gemm<true><<<gemm_grid, 256, 0, stream>>>(K, Wk, bk, kws);
    proj_gemm<true><<<gemm_grid, 256, 0, stream>>>(V, Wv, bv, vws);

    const dim3 attn_grid(S_LEN / 64, NH, BATCH);      // (32, 16, 2)
    flash_attn<<<attn_grid, 256, 0, stream>>>(qws, kws, vws, aws);

    proj_gemm<false><<<gemm_grid, 256, 0, stream>>>(aws, Wo, bo, out);
}

// Round 3
// 325.794 us; speedup vs baseline: 4.1616x; 4.1616x over previous
//
#include <hip/hip_runtime.h>
#include <hip/hip_bf16.h>
#include <math.h>

#define D_MODEL 1024
#define NH      16
#define DK      64
#define S_LEN   2048
#define BATCH   2
#define M_ROWS  4096

typedef _Float16 f16;
typedef _Float16 f16x8 __attribute__((ext_vector_type(8)));
typedef float    f32x4 __attribute__((ext_vector_type(4)));

// ---------------------------------------------------------------------------
// fp32 -> fp16 conversion, 8 elems/thread, up to 4 tensors via blockIdx.y
// ---------------------------------------------------------------------------
__global__ __launch_bounds__(256) void cvt_f32_to_f16(
    const float* __restrict__ a, const float* __restrict__ b,
    const float* __restrict__ c, const float* __restrict__ d,
    f16* __restrict__ oa, f16* __restrict__ ob,
    f16* __restrict__ oc, f16* __restrict__ od, int n8) {
    const int y = blockIdx.y;
    const float* s = (y == 0) ? a : (y == 1) ? b : (y == 2) ? c : d;
    f16* o        = (y == 0) ? oa : (y == 1) ? ob : (y == 2) ? oc : od;
    if (s == nullptr) return;
    const int i = blockIdx.x * 256 + threadIdx.x;
    if (i >= n8) return;
    const size_t e = (size_t)i * 8;
    const float4 v0 = *(const float4*)&s[e];
    const float4 v1 = *(const float4*)&s[e + 4];
    f16x8 r = {(f16)v0.x, (f16)v0.y, (f16)v0.z, (f16)v0.w,
               (f16)v1.x, (f16)v1.y, (f16)v1.z, (f16)v1.w};
    *(f16x8*)&o[e] = r;
}

// ---------------------------------------------------------------------------
// fp16 MFMA GEMM: Y[m][n] = sum_k X[m][k]*W[n][k] + bias[n]
// BM=BN=128, BK=32, 256 threads (4 waves, 2x2), 4x4 16x16x32 MFMAs per wave.
// mode 0: f16 out, head-split [b][h][s][dk]
// mode 1: f16 out, head-split + transposed [b][h][dk][s]
// mode 2: f32 out, plain [m][n]
// ---------------------------------------------------------------------------
__device__ __forceinline__ void gemm_body(const f16* __restrict__ X, const f16* __restrict__ W,
                                          const float* __restrict__ bias, void* __restrict__ Yv,
                                          const int mode) {
    __shared__ f16 As[128][40];   // pad to 40 f16 = 80B rows: 2-way banks (free)
    __shared__ f16 Bs[128][40];
    const int tid = threadIdx.x;
    const int lane = tid & 63;
    const int w  = tid >> 6;
    const int wm = w >> 1, wn = w & 1;
    const int l15 = lane & 15, lhi = lane >> 4;
    const int m0 = blockIdx.y * 128, n0 = blockIdx.x * 128;

    f32x4 acc[4][4] = {};

    const int cr = tid >> 2;          // staging row 0..63 (+64 for 2nd chunk)
    const int cs = (tid & 3) * 8;     // k element offset

    for (int k0 = 0; k0 < D_MODEL; k0 += 32) {
        __syncthreads();
        {
            const uint4 a0 = *(const uint4*)&X[(size_t)(m0 + cr) * D_MODEL + k0 + cs];
            const uint4 a1 = *(const uint4*)&X[(size_t)(m0 + cr + 64) * D_MODEL + k0 + cs];
            const uint4 b0 = *(const uint4*)&W[(size_t)(n0 + cr) * D_MODEL + k0 + cs];
            const uint4 b1 = *(const uint4*)&W[(size_t)(n0 + cr + 64) * D_MODEL + k0 + cs];
            *(uint4*)&As[cr][cs] = a0;
            *(uint4*)&As[cr + 64][cs] = a1;
            *(uint4*)&Bs[cr][cs] = b0;
            *(uint4*)&Bs[cr + 64][cs] = b1;
        }
        __syncthreads();
        f16x8 af[4], bf[4];
#pragma unroll
        for (int mt = 0; mt < 4; ++mt) af[mt] = *(const f16x8*)&As[wm * 64 + mt * 16 + l15][lhi * 8];
#pragma unroll
        for (int nt = 0; nt < 4; ++nt) bf[nt] = *(const f16x8*)&Bs[wn * 64 + nt * 16 + l15][lhi * 8];
#pragma unroll
        for (int mt = 0; mt < 4; ++mt)
#pragma unroll
            for (int nt = 0; nt < 4; ++nt)
                acc[mt][nt] = __builtin_amdgcn_mfma_f32_16x16x32_f16(af[mt], bf[nt], acc[mt][nt], 0, 0, 0);
    }

#pragma unroll
    for (int mt = 0; mt < 4; ++mt)
#pragma unroll
        for (int nt = 0; nt < 4; ++nt) {
            const int n = n0 + wn * 64 + nt * 16 + l15;
            const float bn = bias[n];
#pragma unroll
            for (int r = 0; r < 4; ++r) {
                const int m = m0 + wm * 64 + mt * 16 + lhi * 4 + r;
                const float v = acc[mt][nt][r] + bn;
                if (mode == 0) {
                    ((f16*)Yv)[((((size_t)(m >> 11) * NH + (n >> 6)) * S_LEN) + (m & 2047)) * DK + (n & 63)] = (f16)v;
                } else if (mode == 1) {
                    ((f16*)Yv)[((((size_t)(m >> 11) * NH + (n >> 6)) * DK) + (n & 63)) * S_LEN + (m & 2047)] = (f16)v;
                } else {
                    ((float*)Yv)[(size_t)m * D_MODEL + n] = v;
                }
            }
        }
}

__global__ __launch_bounds__(256) void qkv_gemm(
    const f16* __restrict__ Xq, const f16* __restrict__ Xk, const f16* __restrict__ Xv,
    const f16* __restrict__ Wq, const f16* __restrict__ Wk, const f16* __restrict__ Wv,
    const float* __restrict__ bq, const float* __restrict__ bk, const float* __restrict__ bv,
    f16* __restrict__ qh, f16* __restrict__ kh, f16* __restrict__ vt) {
    const int z = blockIdx.z;
    const f16* X = (z == 0) ? Xq : (z == 1) ? Xk : Xv;
    const f16* W = (z == 0) ? Wq : (z == 1) ? Wk : Wv;
    const float* bias = (z == 0) ? bq : (z == 1) ? bk : bv;
    f16* Y = (z == 0) ? qh : (z == 1) ? kh : vt;
    gemm_body(X, W, bias, Y, (z == 2) ? 1 : 0);
}

__global__ __launch_bounds__(256) void out_gemm(const f16* __restrict__ X, const f16* __restrict__ W,
                                                const float* __restrict__ bias, float* __restrict__ Y) {
    gemm_body(X, W, bias, Y, 2);
}

// ---------------------------------------------------------------------------
// MFMA flash attention. Grid (qt=S/64, bh=32). 4 waves x 16 q-rows each.
// K tiles [64key][64dk] and transposed-V tiles [64dk][64key] staged in LDS
// (padded rows 72 f16 = 144B: 2-way banks). P goes through per-wave LDS to
// re-fragment D-layout -> A-layout. Online softmax in registers.
// ---------------------------------------------------------------------------
__global__ __launch_bounds__(256) void flash_mfma(const f16* __restrict__ qh, const f16* __restrict__ kh,
                                                  const f16* __restrict__ vt, f16* __restrict__ ao) {
    __shared__ f16 Ks[64][72];
    __shared__ f16 Vs[64][72];        // [dk][key]
    __shared__ f16 Ps[4][16][72];     // per-wave P tile [qrow][key]

    const int tid = threadIdx.x;
    const int lane = tid & 63;
    const int w = tid >> 6;
    const int l15 = lane & 15, lhi = lane >> 4;
    const int qt = blockIdx.x, bh = blockIdx.y;
    const int b = bh >> 4, h = bh & 15;
    const int qrow0 = qt * 64 + w * 16;

    f16x8 aQ0, aQ1;
    {
        const f16* qp = qh + ((size_t)bh * S_LEN + qrow0 + l15) * DK;
        aQ0 = *(const f16x8*)&qp[lhi * 8];
        aQ1 = *(const f16x8*)&qp[32 + lhi * 8];
    }

    f32x4 oa[4] = {};
    float m_run[4] = {-INFINITY, -INFINITY, -INFINITY, -INFINITY};
    float l_run[4] = {0.f, 0.f, 0.f, 0.f};

    const int cr = tid >> 3;          // staging row 0..31 (+32 for 2nd chunk)
    const int cs = (tid & 7) * 8;

    for (int kt = 0; kt < S_LEN / 64; ++kt) {
        __syncthreads();
        {
            const uint4 k0v = *(const uint4*)&kh[((size_t)bh * S_LEN + kt * 64 + cr) * DK + cs];
            const uint4 k1v = *(const uint4*)&kh[((size_t)bh * S_LEN + kt * 64 + cr + 32) * DK + cs];
            const uint4 v0v = *(const uint4*)&vt[((size_t)bh * DK + cr) * S_LEN + kt * 64 + cs];
            const uint4 v1v = *(const uint4*)&vt[((size_t)bh * DK + cr + 32) * S_LEN + kt * 64 + cs];
            *(uint4*)&Ks[cr][cs] = k0v;
            *(uint4*)&Ks[cr + 32][cs] = k1v;
            *(uint4*)&Vs[cr][cs] = v0v;
            *(uint4*)&Vs[cr + 32][cs] = v1v;
        }
        __syncthreads();

        // QK^T: wave's 16 q-rows x 64 keys
        f32x4 sc[4] = {};
#pragma unroll
        for (int nt = 0; nt < 4; ++nt) {
            const f16x8 b0 = *(const f16x8*)&Ks[nt * 16 + l15][lhi * 8];
            const f16x8 b1 = *(const f16x8*)&Ks[nt * 16 + l15][32 + lhi * 8];
            sc[nt] = __builtin_amdgcn_mfma_f32_16x16x32_f16(aQ0, b0, sc[nt], 0, 0, 0);
            sc[nt] = __builtin_amdgcn_mfma_f32_16x16x32_f16(aQ1, b1, sc[nt], 0, 0, 0);
        }

        // online softmax (rows spread over 16-lane groups)
#pragma unroll
        for (int r = 0; r < 4; ++r) {
            const float s0 = sc[0][r] * 0.125f, s1 = sc[1][r] * 0.125f;
            const float s2 = sc[2][r] * 0.125f, s3 = sc[3][r] * 0.125f;
            float t = fmaxf(fmaxf(s0, s1), fmaxf(s2, s3));
            t = fmaxf(t, __shfl_xor(t, 1));
            t = fmaxf(t, __shfl_xor(t, 2));
            t = fmaxf(t, __shfl_xor(t, 4));
            t = fmaxf(t, __shfl_xor(t, 8));
            const float mnew = fmaxf(m_run[r], t);
            const float fac = __expf(m_run[r] - mnew);
            m_run[r] = mnew;
            const float p0 = __expf(s0 - mnew), p1 = __expf(s1 - mnew);
            const float p2 = __expf(s2 - mnew), p3 = __expf(s3 - mnew);
            float sum = p0 + p1 + p2 + p3;
            sum += __shfl_xor(sum, 1);
            sum += __shfl_xor(sum, 2);
            sum += __shfl_xor(sum, 4);
            sum += __shfl_xor(sum, 8);
            l_run[r] = l_run[r] * fac + sum;
            oa[0][r] *= fac; oa[1][r] *= fac; oa[2][r] *= fac; oa[3][r] *= fac;
            const int prow = lhi * 4 + r;
            Ps[w][prow][l15]      = (f16)p0;
            Ps[w][prow][16 + l15] = (f16)p1;
            Ps[w][prow][32 + l15] = (f16)p2;
            Ps[w][prow][48 + l15] = (f16)p3;
        }

        // PV: A = P (from LDS, A-layout), B = V via transposed tile
        const f16x8 aP0 = *(const f16x8*)&Ps[w][l15][lhi * 8];
        const f16x8 aP1 = *(const f16x8*)&Ps[w][l15][32 + lhi * 8];
#pragma unroll
        for (int nt = 0; nt < 4; ++nt) {
            const f16x8 b0 = *(const f16x8*)&Vs[nt * 16 + l15][lhi * 8];
            const f16x8 b1 = *(const f16x8*)&Vs[nt * 16 + l15][32 + lhi * 8];
            oa[nt] = __builtin_amdgcn_mfma_f32_16x16x32_f16(aP0, b0, oa[nt], 0, 0, 0);
            oa[nt] = __builtin_amdgcn_mfma_f32_16x16x32_f16(aP1, b1, oa[nt], 0, 0, 0);
        }
    }

    // epilogue: write [B][S][D_MODEL] f16 (input to output GEMM)
#pragma unroll
    for (int r = 0; r < 4; ++r) {
        const float inv = 1.f / l_run[r];
        const int srow = qrow0 + lhi * 4 + r;
#pragma unroll
        for (int nt = 0; nt < 4; ++nt) {
            ao[((size_t)b * S_LEN + srow) * D_MODEL + h * DK + nt * 16 + l15] = (f16)(oa[nt][r] * inv);
        }
    }
}

// ---------------------------------------------------------------------------
extern "C" void kernel_launch(void* const* d_in, const int* in_sizes, int n_in,
                              void* d_out, int out_size, void* d_ws, size_t ws_size,
                              hipStream_t stream) {
    const float* Q  = (const float*)d_in[0];
    const float* K  = (const float*)d_in[1];
    const float* V  = (const float*)d_in[2];
    const float* Wq = (const float*)d_in[3];
    const float* bq = (const float*)d_in[4];
    const float* Wk = (const float*)d_in[5];
    const float* bk = (const float*)d_in[6];
    const float* Wv = (const float*)d_in[7];
    const float* bv = (const float*)d_in[8];
    const float* Wo = (const float*)d_in[9];
    const float* bo = (const float*)d_in[10];
    float* out = (float*)d_out;

    const size_t NELEM = (size_t)M_ROWS * D_MODEL;   // 4M
    const size_t WELEM = (size_t)D_MODEL * D_MODEL;  // 1M
    f16* Qf  = (f16*)d_ws;
    f16* Kf  = Qf + NELEM;
    f16* Vf  = Kf + NELEM;
    f16* Wqf = Vf + NELEM;
    f16* Wkf = Wqf + WELEM;
    f16* Wvf = Wkf + WELEM;
    f16* Wof = Wvf + WELEM;
    f16* qh  = Wof + WELEM;   // [bh][s][dk]
    f16* kh  = qh + NELEM;    // [bh][s][dk]
    f16* vtw = kh + NELEM;    // [bh][dk][s]
    f16* aow = vtw + NELEM;   // [b][s][d_model]
    // total: 32M f16 = 64MB

    cvt_f32_to_f16<<<dim3(2048, 3), 256, 0, stream>>>(Q, K, V, nullptr, Qf, Kf, Vf, nullptr,
                                                      (int)(NELEM / 8));
    cvt_f32_to_f16<<<dim3(512, 4), 256, 0, stream>>>(Wq, Wk, Wv, Wo, Wqf, Wkf, Wvf, Wof,
                                                     (int)(WELEM / 8));
    qkv_gemm<<<dim3(D_MODEL / 128, M_ROWS / 128, 3), 256, 0, stream>>>(
        Qf, Kf, Vf, Wqf, Wkf, Wvf, bq, bk, bv, qh, kh, vtw);
    flash_mfma<<<dim3(S_LEN / 64, BATCH * NH), 256, 0, stream>>>(qh, kh, vtw, aow);
    out_gemm<<<dim3(D_MODEL / 128, M_ROWS / 128), 256, 0, stream>>>(aow, Wof, bo, out);
}

// Round 5
// 279.488 us; speedup vs baseline: 4.8511x; 1.1657x over previous
//
#include <hip/hip_runtime.h>
#include <hip/hip_bf16.h>
#include <math.h>

#define D_MODEL 1024
#define NH      16
#define DK      64
#define S_LEN   2048
#define BATCH   2
#define M_ROWS  4096

typedef _Float16 f16;
typedef _Float16 f16x4 __attribute__((ext_vector_type(4)));
typedef _Float16 f16x8 __attribute__((ext_vector_type(8)));
typedef float    f32x4 __attribute__((ext_vector_type(4)));

// ---------------------------------------------------------------------------
// fp32 -> fp16 conversion, 8 elems/thread, up to 4 tensors via blockIdx.y
// ---------------------------------------------------------------------------
__global__ __launch_bounds__(256) void cvt_f32_to_f16(
    const float* __restrict__ a, const float* __restrict__ b,
    const float* __restrict__ c, const float* __restrict__ d,
    f16* __restrict__ oa, f16* __restrict__ ob,
    f16* __restrict__ oc, f16* __restrict__ od, int n8) {
    const int y = blockIdx.y;
    const float* s = (y == 0) ? a : (y == 1) ? b : (y == 2) ? c : d;
    f16* o        = (y == 0) ? oa : (y == 1) ? ob : (y == 2) ? oc : od;
    if (s == nullptr) return;
    const int i = blockIdx.x * 256 + threadIdx.x;
    if (i >= n8) return;
    const size_t e = (size_t)i * 8;
    const float4 v0 = *(const float4*)&s[e];
    const float4 v1 = *(const float4*)&s[e + 4];
    f16x8 r = {(f16)v0.x, (f16)v0.y, (f16)v0.z, (f16)v0.w,
               (f16)v1.x, (f16)v1.y, (f16)v1.z, (f16)v1.w};
    *(f16x8*)&o[e] = r;
}

// ---------------------------------------------------------------------------
// async global->LDS staging, 16B per lane (HW: wave-uniform base + lane*16)
// ---------------------------------------------------------------------------
__device__ __forceinline__ void stage16(const f16* g, f16* l) {
    __builtin_amdgcn_global_load_lds(
        (const __attribute__((address_space(1))) unsigned int*)g,
        (__attribute__((address_space(3))) unsigned int*)l, 16, 0, 0);
}

// ---------------------------------------------------------------------------
// fp16 MFMA GEMM: Y[m][n] = sum_k X[m][k]*W[n][k] + bias[n]  (then *oscale)
// BM=BN=128, BK=32, 256 threads (4 waves, 2x2), global_load_lds staging into
// LINEAR LDS [128][32] f16 (m97 structure).
// mode 0: f16 out, head-split [b][h][s][dk]
// mode 1: f16 out, head-split + transposed [b][h][dk][s]
// mode 2: f32 out, plain [m][n]
// ---------------------------------------------------------------------------
__device__ __forceinline__ void gemm_body(const f16* __restrict__ X, const f16* __restrict__ W,
                                          const float* __restrict__ bias, void* __restrict__ Yv,
                                          const int mode, const float oscale) {
    __shared__ f16 As[128 * 32];   // linear: row r at f16-offset r*32
    __shared__ f16 Bs[128 * 32];
    const int tid = threadIdx.x;
    const int lane = tid & 63;
    const int w  = tid >> 6;
    const int wm = w >> 1, wn = w & 1;
    const int l15 = lane & 15, lhi = lane >> 4;
    const int m0 = blockIdx.y * 128, n0 = blockIdx.x * 128;

    // staging: thread tid loads 16B -> rows tid>>2 (+64), col (tid&3)*8
    const int srow = tid >> 2;
    const int scol = (tid & 3) * 8;

    f32x4 acc[4][4] = {};

    for (int k0 = 0; k0 < D_MODEL; k0 += 32) {
        __syncthreads();
        stage16(&X[(size_t)(m0 + srow) * D_MODEL + k0 + scol],      &As[tid * 8]);
        stage16(&X[(size_t)(m0 + 64 + srow) * D_MODEL + k0 + scol], &As[2048 + tid * 8]);
        stage16(&W[(size_t)(n0 + srow) * D_MODEL + k0 + scol],      &Bs[tid * 8]);
        stage16(&W[(size_t)(n0 + 64 + srow) * D_MODEL + k0 + scol], &Bs[2048 + tid * 8]);
        __syncthreads();   // compiler drains vmcnt before barrier
        f16x8 af[4], bf[4];
#pragma unroll
        for (int mt = 0; mt < 4; ++mt) af[mt] = *(const f16x8*)&As[(wm * 64 + mt * 16 + l15) * 32 + lhi * 8];
#pragma unroll
        for (int nt = 0; nt < 4; ++nt) bf[nt] = *(const f16x8*)&Bs[(wn * 64 + nt * 16 + l15) * 32 + lhi * 8];
#pragma unroll
        for (int mt = 0; mt < 4; ++mt)
#pragma unroll
            for (int nt = 0; nt < 4; ++nt)
                acc[mt][nt] = __builtin_amdgcn_mfma_f32_16x16x32_f16(af[mt], bf[nt], acc[mt][nt], 0, 0, 0);
    }

#pragma unroll
    for (int mt = 0; mt < 4; ++mt)
#pragma unroll
        for (int nt = 0; nt < 4; ++nt) {
            const int n = n0 + wn * 64 + nt * 16 + l15;
            const float bn = bias[n];
#pragma unroll
            for (int r = 0; r < 4; ++r) {
                const int m = m0 + wm * 64 + mt * 16 + lhi * 4 + r;
                const float v = (acc[mt][nt][r] + bn) * oscale;
                if (mode == 0) {
                    ((f16*)Yv)[((((size_t)(m >> 11) * NH + (n >> 6)) * S_LEN) + (m & 2047)) * DK + (n & 63)] = (f16)v;
                } else if (mode == 1) {
                    ((f16*)Yv)[((((size_t)(m >> 11) * NH + (n >> 6)) * DK) + (n & 63)) * S_LEN + (m & 2047)] = (f16)v;
                } else {
                    ((float*)Yv)[(size_t)m * D_MODEL + n] = v;
                }
            }
        }
}

__global__ __launch_bounds__(256) void qkv_gemm(
    const f16* __restrict__ Xq, const f16* __restrict__ Xk, const f16* __restrict__ Xv,
    const f16* __restrict__ Wq, const f16* __restrict__ Wk, const f16* __restrict__ Wv,
    const float* __restrict__ bq, const float* __restrict__ bk, const float* __restrict__ bv,
    f16* __restrict__ qh, f16* __restrict__ kh, f16* __restrict__ vt) {
    const int z = blockIdx.z;
    const f16* X = (z == 0) ? Xq : (z == 1) ? Xk : Xv;
    const f16* W = (z == 0) ? Wq : (z == 1) ? Wk : Wv;
    const float* bias = (z == 0) ? bq : (z == 1) ? bk : bv;
    f16* Y = (z == 0) ? qh : (z == 1) ? kh : vt;
    // fold softmax scale 1/sqrt(64) into the Q projection
    gemm_body(X, W, bias, Y, (z == 2) ? 1 : 0, (z == 0) ? 0.125f : 1.0f);
}

__global__ __launch_bounds__(256) void out_gemm(const f16* __restrict__ X, const f16* __restrict__ W,
                                                const float* __restrict__ bias, float* __restrict__ Y) {
    gemm_body(X, W, bias, Y, 2, 1.0f);
}

// ---------------------------------------------------------------------------
// MFMA flash attention, swapped QK^T. Grid (qt=S/64, bh=32). 4 waves x 16 q.
// QK^T computed as mfma(K, Q) -> D[key][q]: lane (g=lane>>4, c=lane&15) holds
// S[key = nt*16+g*4+r][q=c] -> softmax is lane-local over 16 keys + 2 shfls.
// PV key-permutation pi(t) = (d>>1)*16 + g*4 + (d&1)*2 + b makes the PV
// A-fragment equal the lane's OWN exp values (zero shuffles, no P-LDS);
// V is read with the same key order (2x b64 per fragment half).
// ---------------------------------------------------------------------------
__global__ __launch_bounds__(256) void flash_mfma(const f16* __restrict__ qh, const f16* __restrict__ kh,
                                                  const f16* __restrict__ vt, f16* __restrict__ ao) {
    __shared__ f16 Ks[64][72];    // [key][dk]
    __shared__ f16 Vs[64][72];    // [dk][key]

    const int tid = threadIdx.x;
    const int lane = tid & 63;
    const int w = tid >> 6;
    const int c = lane & 15;      // q column (softmax coords / PV A-row)
    const int g = lane >> 4;      // lane group
    const int qt = blockIdx.x, bh = blockIdx.y;
    const int b = bh >> 4, h = bh & 15;
    const int qrow0 = qt * 64 + w * 16;

    // Q as B-operand: B[k=dk][col=q=c] -> Q[q=c][dk = g*8+j] (Q pre-scaled by 0.125)
    f16x8 bQ0, bQ1;
    {
        const f16* qp = qh + ((size_t)bh * S_LEN + qrow0 + c) * DK;
        bQ0 = *(const f16x8*)&qp[g * 8];
        bQ1 = *(const f16x8*)&qp[32 + g * 8];
    }

    f32x4 oa[4] = {};                 // O[q = g*4+r][d = nt2*16+c]
    float m_run = -INFINITY;          // for q = c (replicated across groups)
    float l_run = 0.f;

    const int cr = tid >> 3;          // staging row 0..31 (+32)
    const int cs = (tid & 7) * 8;

    for (int kt = 0; kt < S_LEN / 64; ++kt) {
        __syncthreads();
        {
            const uint4 k0v = *(const uint4*)&kh[((size_t)bh * S_LEN + kt * 64 + cr) * DK + cs];
            const uint4 k1v = *(const uint4*)&kh[((size_t)bh * S_LEN + kt * 64 + cr + 32) * DK + cs];
            const uint4 v0v = *(const uint4*)&vt[((size_t)bh * DK + cr) * S_LEN + kt * 64 + cs];
            const uint4 v1v = *(const uint4*)&vt[((size_t)bh * DK + cr + 32) * S_LEN + kt * 64 + cs];
            *(uint4*)&Ks[cr][cs] = k0v;
            *(uint4*)&Ks[cr + 32][cs] = k1v;
            *(uint4*)&Vs[cr][cs] = v0v;
            *(uint4*)&Vs[cr + 32][cs] = v1v;
        }
        __syncthreads();

        // swapped QK^T: sc[nt][r] = S[key = nt*16 + g*4 + r][q = c]
        f32x4 sc[4] = {};
#pragma unroll
        for (int nt = 0; nt < 4; ++nt) {
            const f16x8 ka = *(const f16x8*)&Ks[nt * 16 + c][g * 8];
            const f16x8 kb = *(const f16x8*)&Ks[nt * 16 + c][32 + g * 8];
            sc[nt] = __builtin_amdgcn_mfma_f32_16x16x32_f16(ka, bQ0, sc[nt], 0, 0, 0);
            sc[nt] = __builtin_amdgcn_mfma_f32_16x16x32_f16(kb, bQ1, sc[nt], 0, 0, 0);
        }

        // softmax for q=c: local max over 16 keys + 2 cross-group shfls
        float tmax = sc[0][0];
#pragma unroll
        for (int nt = 0; nt < 4; ++nt)
#pragma unroll
            for (int r = 0; r < 4; ++r) tmax = fmaxf(tmax, sc[nt][r]);
        tmax = fmaxf(tmax, __shfl_xor(tmax, 16));
        tmax = fmaxf(tmax, __shfl_xor(tmax, 32));
        const float mnew = fmaxf(m_run, tmax);
        const float fac = __expf(m_run - mnew);
        m_run = mnew;

        float e[4][4];
        float tsum = 0.f;
#pragma unroll
        for (int nt = 0; nt < 4; ++nt)
#pragma unroll
            for (int r = 0; r < 4; ++r) {
                e[nt][r] = __expf(sc[nt][r] - mnew);
                tsum += e[nt][r];
            }
        tsum += __shfl_xor(tsum, 16);
        tsum += __shfl_xor(tsum, 32);
        l_run = l_run * fac + tsum;

        // rescale O: row r corresponds to q = g*4 + r -> pull fac from lane (g*16 + g*4 + r)
#pragma unroll
        for (int r = 0; r < 4; ++r) {
            const float fr = __shfl(fac, (lane & 48) + ((lane >> 4) & 3) * 4 + r);
            oa[0][r] *= fr; oa[1][r] *= fr; oa[2][r] *= fr; oa[3][r] *= fr;
        }

        // PV A-fragments are the lane's own exp values (key order pi)
        const f16x8 aP0 = {(f16)e[0][0], (f16)e[0][1], (f16)e[0][2], (f16)e[0][3],
                           (f16)e[1][0], (f16)e[1][1], (f16)e[1][2], (f16)e[1][3]};
        const f16x8 aP1 = {(f16)e[2][0], (f16)e[2][1], (f16)e[2][2], (f16)e[2][3],
                           (f16)e[3][0], (f16)e[3][1], (f16)e[3][2], (f16)e[3][3]};

        // B: V[key=pi(k-slot)][d], matching key order: j0..3 -> keys g*4+.., j4..7 -> 16+g*4+..
#pragma unroll
        for (int nt2 = 0; nt2 < 4; ++nt2) {
            union { f16x8 v; f16x4 q[2]; } b0, b1;
            b0.q[0] = *(const f16x4*)&Vs[nt2 * 16 + c][g * 4];
            b0.q[1] = *(const f16x4*)&Vs[nt2 * 16 + c][16 + g * 4];
            b1.q[0] = *(const f16x4*)&Vs[nt2 * 16 + c][32 + g * 4];
            b1.q[1] = *(const f16x4*)&Vs[nt2 * 16 + c][48 + g * 4];
            oa[nt2] = __builtin_amdgcn_mfma_f32_16x16x32_f16(aP0, b0.v, oa[nt2], 0, 0, 0);
            oa[nt2] = __builtin_amdgcn_mfma_f32_16x16x32_f16(aP1, b1.v, oa[nt2], 0, 0, 0);
        }
    }

    // epilogue: O row q = g*4+r, col d = nt2*16+c; pull 1/l from softmax coords
    const float invc = 1.f / l_run;
#pragma unroll
    for (int r = 0; r < 4; ++r) {
        const float ir = __shfl(invc, (lane & 48) + ((lane >> 4) & 3) * 4 + r);
        const int srow = qrow0 + ((lane >> 4) & 3) * 4 + r;
#pragma unroll
        for (int nt2 = 0; nt2 < 4; ++nt2) {
            ao[((size_t)b * S_LEN + srow) * D_MODEL + h * DK + nt2 * 16 + c] = (f16)(oa[nt2][r] * ir);
        }
    }
}

// ---------------------------------------------------------------------------
extern "C" void kernel_launch(void* const* d_in, const int* in_sizes, int n_in,
                              void* d_out, int out_size, void* d_ws, size_t ws_size,
                              hipStream_t stream) {
    const float* Q  = (const float*)d_in[0];
    const float* K  = (const float*)d_in[1];
    const float* V  = (const float*)d_in[2];
    const float* Wq = (const float*)d_in[3];
    const float* bq = (const float*)d_in[4];
    const float* Wk = (const float*)d_in[5];
    const float* bk = (const float*)d_in[6];
    const float* Wv = (const float*)d_in[7];
    const float* bv = (const float*)d_in[8];
    const float* Wo = (const float*)d_in[9];
    const float* bo = (const float*)d_in[10];
    float* out = (float*)d_out;

    const size_t NELEM = (size_t)M_ROWS * D_MODEL;   // 4M
    const size_t WELEM = (size_t)D_MODEL * D_MODEL;  // 1M
    f16* Qf  = (f16*)d_ws;
    f16* Kf  = Qf + NELEM;
    f16* Vf  = Kf + NELEM;
    f16* Wqf = Vf + NELEM;
    f16* Wkf = Wqf + WELEM;
    f16* Wvf = Wkf + WELEM;
    f16* Wof = Wvf + WELEM;
    f16* qh  = Wof + WELEM;   // [bh][s][dk]  (pre-scaled by 0.125)
    f16* kh  = qh + NELEM;    // [bh][s][dk]
    f16* vtw = kh + NELEM;    // [bh][dk][s]
    f16* aow = vtw + NELEM;   // [b][s][d_model]

    cvt_f32_to_f16<<<dim3(2048, 3), 256, 0, stream>>>(Q, K, V, nullptr, Qf, Kf, Vf, nullptr,
                                                      (int)(NELEM / 8));
    cvt_f32_to_f16<<<dim3(512, 4), 256, 0, stream>>>(Wq, Wk, Wv, Wo, Wqf, Wkf, Wvf, Wof,
                                                     (int)(WELEM / 8));
    qkv_gemm<<<dim3(D_MODEL / 128, M_ROWS / 128, 3), 256, 0, stream>>>(
        Qf, Kf, Vf, Wqf, Wkf, Wvf, bq, bk, bv, qh, kh, vtw);
    flash_mfma<<<dim3(S_LEN / 64, BATCH * NH), 256, 0, stream>>>(qh, kh, vtw, aow);
    out_gemm<<<dim3(D_MODEL / 128, M_ROWS / 128), 256, 0, stream>>>(aow, Wof, bo, out);
}

// Round 6
// 251.482 us; speedup vs baseline: 5.3913x; 1.1114x over previous
//
#include <hip/hip_runtime.h>
#include <hip/hip_bf16.h>
#include <math.h>

#define D_MODEL 1024
#define NH      16
#define DK      64
#define S_LEN   2048
#define BATCH   2
#define M_ROWS  4096

typedef _Float16 f16;
typedef _Float16 f16x8 __attribute__((ext_vector_type(8)));
typedef float    f32x4 __attribute__((ext_vector_type(4)));

// native 2^x (v_exp_f32)
__device__ __forceinline__ float exp2_fast(float x) {
    float r;
    asm("v_exp_f32 %0, %1" : "=v"(r) : "v"(x));
    return r;
}

// V key permutation within a 64-block: key' = [b5][b3 b2][b4][b1 b0]
// so that PV A-fragment key order pi(k)=g*8+j matches contiguous LDS reads.
__device__ __forceinline__ int perm6(int k) {
    return (k & 35) | ((k & 12) << 1) | ((k & 16) >> 2);
}

// ---------------------------------------------------------------------------
// fp32 -> fp16 conversion, 8 elems/thread, up to 4 tensors via blockIdx.y
// ---------------------------------------------------------------------------
__global__ __launch_bounds__(256) void cvt_f32_to_f16(
    const float* __restrict__ a, const float* __restrict__ b,
    const float* __restrict__ c, const float* __restrict__ d,
    f16* __restrict__ oa, f16* __restrict__ ob,
    f16* __restrict__ oc, f16* __restrict__ od, int n8) {
    const int y = blockIdx.y;
    const float* s = (y == 0) ? a : (y == 1) ? b : (y == 2) ? c : d;
    f16* o        = (y == 0) ? oa : (y == 1) ? ob : (y == 2) ? oc : od;
    if (s == nullptr) return;
    const int i = blockIdx.x * 256 + threadIdx.x;
    if (i >= n8) return;
    const size_t e = (size_t)i * 8;
    const float4 v0 = *(const float4*)&s[e];
    const float4 v1 = *(const float4*)&s[e + 4];
    f16x8 r = {(f16)v0.x, (f16)v0.y, (f16)v0.z, (f16)v0.w,
               (f16)v1.x, (f16)v1.y, (f16)v1.z, (f16)v1.w};
    *(f16x8*)&o[e] = r;
}

// ---------------------------------------------------------------------------
// async global->LDS staging, 16B per lane (HW: wave-uniform base + lane*16)
// ---------------------------------------------------------------------------
__device__ __forceinline__ void stage16(const f16* g, f16* l) {
    __builtin_amdgcn_global_load_lds(
        (const __attribute__((address_space(1))) unsigned int*)g,
        (__attribute__((address_space(3))) unsigned int*)l, 16, 0, 0);
}

// ---------------------------------------------------------------------------
// 128x128 fp16 MFMA GEMM body (normal orientation).
// mode 0: f16 out head-split [b][h][s][dk]; mode 2: f32 out [m][n].
// ---------------------------------------------------------------------------
__device__ __forceinline__ void gemm_body(f16* As, f16* Bs,
                                          const f16* __restrict__ X, const f16* __restrict__ W,
                                          const float* __restrict__ bias, void* __restrict__ Yv,
                                          const int mode, const float oscale) {
    const int tid = threadIdx.x;
    const int lane = tid & 63;
    const int w  = tid >> 6;
    const int wm = w >> 1, wn = w & 1;
    const int l15 = lane & 15, lhi = lane >> 4;
    const int m0 = blockIdx.y * 128, n0 = blockIdx.x * 128;

    const int srow = tid >> 2;
    const int scol = (tid & 3) * 8;

    f32x4 acc[4][4] = {};

    for (int k0 = 0; k0 < D_MODEL; k0 += 32) {
        __syncthreads();
        stage16(&X[(size_t)(m0 + srow) * D_MODEL + k0 + scol],      &As[tid * 8]);
        stage16(&X[(size_t)(m0 + 64 + srow) * D_MODEL + k0 + scol], &As[2048 + tid * 8]);
        stage16(&W[(size_t)(n0 + srow) * D_MODEL + k0 + scol],      &Bs[tid * 8]);
        stage16(&W[(size_t)(n0 + 64 + srow) * D_MODEL + k0 + scol], &Bs[2048 + tid * 8]);
        __syncthreads();
        f16x8 af[4], bf[4];
#pragma unroll
        for (int mt = 0; mt < 4; ++mt) af[mt] = *(const f16x8*)&As[(wm * 64 + mt * 16 + l15) * 32 + lhi * 8];
#pragma unroll
        for (int nt = 0; nt < 4; ++nt) bf[nt] = *(const f16x8*)&Bs[(wn * 64 + nt * 16 + l15) * 32 + lhi * 8];
#pragma unroll
        for (int mt = 0; mt < 4; ++mt)
#pragma unroll
            for (int nt = 0; nt < 4; ++nt)
                acc[mt][nt] = __builtin_amdgcn_mfma_f32_16x16x32_f16(af[mt], bf[nt], acc[mt][nt], 0, 0, 0);
    }

#pragma unroll
    for (int mt = 0; mt < 4; ++mt)
#pragma unroll
        for (int nt = 0; nt < 4; ++nt) {
            const int n = n0 + wn * 64 + nt * 16 + l15;
            const float bn = bias[n];
#pragma unroll
            for (int r = 0; r < 4; ++r) {
                const int m = m0 + wm * 64 + mt * 16 + lhi * 4 + r;
                const float v = (acc[mt][nt][r] + bn) * oscale;
                if (mode == 0) {
                    ((f16*)Yv)[((((size_t)(m >> 11) * NH + (n >> 6)) * S_LEN) + (m & 2047)) * DK + (n & 63)] = (f16)v;
                } else {
                    ((float*)Yv)[(size_t)m * D_MODEL + n] = v;
                }
            }
        }
}

// ---------------------------------------------------------------------------
// 128x128 OPERAND-SWAPPED body for the V projection: A=W rows (n), B=X rows
// (m) -> D[row=n][col=m]. Lanes run along m=s -> coalesced writes into the
// transposed, key-permuted layout vt[bh][dk][s'] (s' = perm6 within 64-block).
// ---------------------------------------------------------------------------
__device__ __forceinline__ void gemm_body_vswap(f16* As, f16* Bs,
                                                const f16* __restrict__ X, const f16* __restrict__ W,
                                                const float* __restrict__ bias, f16* __restrict__ vt) {
    const int tid = threadIdx.x;
    const int lane = tid & 63;
    const int w  = tid >> 6;
    const int wm = w >> 1, wn = w & 1;
    const int l15 = lane & 15, lhi = lane >> 4;
    const int m0 = blockIdx.y * 128, n0 = blockIdx.x * 128;

    const int srow = tid >> 2;
    const int scol = (tid & 3) * 8;

    f32x4 acc[4][4] = {};

    for (int k0 = 0; k0 < D_MODEL; k0 += 32) {
        __syncthreads();
        stage16(&X[(size_t)(m0 + srow) * D_MODEL + k0 + scol],      &As[tid * 8]);
        stage16(&X[(size_t)(m0 + 64 + srow) * D_MODEL + k0 + scol], &As[2048 + tid * 8]);
        stage16(&W[(size_t)(n0 + srow) * D_MODEL + k0 + scol],      &Bs[tid * 8]);
        stage16(&W[(size_t)(n0 + 64 + srow) * D_MODEL + k0 + scol], &Bs[2048 + tid * 8]);
        __syncthreads();
        f16x8 af[4], bf[4];
#pragma unroll
        for (int at = 0; at < 4; ++at) af[at] = *(const f16x8*)&Bs[(wm * 64 + at * 16 + l15) * 32 + lhi * 8];
#pragma unroll
        for (int bt = 0; bt < 4; ++bt) bf[bt] = *(const f16x8*)&As[(wn * 64 + bt * 16 + l15) * 32 + lhi * 8];
#pragma unroll
        for (int at = 0; at < 4; ++at)
#pragma unroll
            for (int bt = 0; bt < 4; ++bt)
                acc[at][bt] = __builtin_amdgcn_mfma_f32_16x16x32_f16(af[at], bf[bt], acc[at][bt], 0, 0, 0);
    }

    // D[row = n-side][col = m-side]
#pragma unroll
    for (int at = 0; at < 4; ++at)
#pragma unroll
        for (int bt = 0; bt < 4; ++bt) {
            const int m = m0 + wn * 64 + bt * 16 + l15;   // = b*2048 + s
            const int b = m >> 11, s = m & 2047;
#pragma unroll
            for (int r = 0; r < 4; ++r) {
                const int n = n0 + wm * 64 + at * 16 + lhi * 4 + r;  // = h*64 + d
                const float v = acc[at][bt][r] + bias[n];
                const int s2 = (s & ~63) | perm6(s & 63);
                vt[(((size_t)b * NH + (n >> 6)) * DK + (n & 63)) * S_LEN + s2] = (f16)v;
            }
        }
}

__global__ __launch_bounds__(256) void qkv_gemm(
    const f16* __restrict__ Xq, const f16* __restrict__ Xk, const f16* __restrict__ Xv,
    const f16* __restrict__ Wq, const f16* __restrict__ Wk, const f16* __restrict__ Wv,
    const float* __restrict__ bq, const float* __restrict__ bk, const float* __restrict__ bv,
    f16* __restrict__ qh, f16* __restrict__ kh, f16* __restrict__ vt) {
    __shared__ f16 As[128 * 32];
    __shared__ f16 Bs[128 * 32];
    const int z = blockIdx.z;
    if (z == 2) {
        gemm_body_vswap(As, Bs, Xv, Wv, bv, vt);
    } else if (z == 0) {
        // fold softmax scale 1/sqrt(64) AND log2(e) into Q projection
        gemm_body(As, Bs, Xq, Wq, bq, qh, 0, 0.125f * 1.44269504f);
    } else {
        gemm_body(As, Bs, Xk, Wk, bk, kh, 0, 1.0f);
    }
}

// ---------------------------------------------------------------------------
// Output GEMM, 64x128 tiles (grid 8x64 = 512 blocks = 2/CU), f32 out.
// 4 waves side-by-side in n (each 64x32), acc[4][2].
// ---------------------------------------------------------------------------
__global__ __launch_bounds__(256) void out_gemm(const f16* __restrict__ X, const f16* __restrict__ W,
                                                const float* __restrict__ bias, float* __restrict__ Y) {
    __shared__ f16 As[64 * 32];    // 4 KB
    __shared__ f16 Bs[128 * 32];   // 8 KB
    const int tid = threadIdx.x;
    const int lane = tid & 63;
    const int w  = tid >> 6;
    const int l15 = lane & 15, lhi = lane >> 4;
    const int m0 = blockIdx.y * 64, n0 = blockIdx.x * 128;

    const int srow = tid >> 2;
    const int scol = (tid & 3) * 8;

    f32x4 acc[4][2] = {};

    for (int k0 = 0; k0 < D_MODEL; k0 += 32) {
        __syncthreads();
        stage16(&X[(size_t)(m0 + srow) * D_MODEL + k0 + scol],      &As[tid * 8]);
        stage16(&W[(size_t)(n0 + srow) * D_MODEL + k0 + scol],      &Bs[tid * 8]);
        stage16(&W[(size_t)(n0 + 64 + srow) * D_MODEL + k0 + scol], &Bs[2048 + tid * 8]);
        __syncthreads();
        f16x8 af[4], bf[2];
#pragma unroll
        for (int mt = 0; mt < 4; ++mt) af[mt] = *(const f16x8*)&As[(mt * 16 + l15) * 32 + lhi * 8];
#pragma unroll
        for (int nt = 0; nt < 2; ++nt) bf[nt] = *(const f16x8*)&Bs[(w * 32 + nt * 16 + l15) * 32 + lhi * 8];
#pragma unroll
        for (int mt = 0; mt < 4; ++mt)
#pragma unroll
            for (int nt = 0; nt < 2; ++nt)
                acc[mt][nt] = __builtin_amdgcn_mfma_f32_16x16x32_f16(af[mt], bf[nt], acc[mt][nt], 0, 0, 0);
    }

#pragma unroll
    for (int mt = 0; mt < 4; ++mt)
#pragma unroll
        for (int nt = 0; nt < 2; ++nt) {
            const int n = n0 + w * 32 + nt * 16 + l15;
            const float bn = bias[n];
#pragma unroll
            for (int r = 0; r < 4; ++r) {
                const int m = m0 + mt * 16 + lhi * 4 + r;
                Y[(size_t)m * D_MODEL + n] = acc[mt][nt][r] + bn;
            }
        }
}

// ---------------------------------------------------------------------------
// MFMA flash attention, swapped QK^T, exp2-space softmax, defer-max,
// async reg-staged K/V prefetch (T14), key-permuted V for b128 PV reads.
// Grid (qt=S/64, bh=32). 4 waves x 16 q-rows.
// ---------------------------------------------------------------------------
__global__ __launch_bounds__(256) void flash_mfma(const f16* __restrict__ qh, const f16* __restrict__ kh,
                                                  const f16* __restrict__ vt, f16* __restrict__ ao) {
    __shared__ f16 Ks[64][72];    // [key][dk]
    __shared__ f16 Vs[64][72];    // [dk][key'] (perm6 key order)

    const int tid = threadIdx.x;
    const int lane = tid & 63;
    const int w = tid >> 6;
    const int c = lane & 15;      // q column (softmax owner) / d column (PV)
    const int g = lane >> 4;
    const int qt = blockIdx.x, bh = blockIdx.y;
    const int b = bh >> 4, h = bh & 15;
    const int qrow0 = qt * 64 + w * 16;

    // Q as B-operand (pre-scaled by 0.125*log2e in the projection)
    f16x8 bQ0, bQ1;
    {
        const f16* qp = qh + ((size_t)bh * S_LEN + qrow0 + c) * DK;
        bQ0 = *(const f16x8*)&qp[g * 8];
        bQ1 = *(const f16x8*)&qp[32 + g * 8];
    }

    f32x4 oa[4] = {};                 // O[q=g*4+r][d=nt2*16+c]
    float m_run = -INFINITY;          // log2-space running max for q=c
    float l_run = 0.f;

    const int cr = tid >> 3;          // staging row 0..31 (+32)
    const int cs = (tid & 7) * 8;

    const f16* kbase = kh + (size_t)bh * S_LEN * DK;
    const f16* vbase = vt + (size_t)bh * DK * S_LEN;

    // prologue: reg-stage tile 0
    uint4 kA = *(const uint4*)&kbase[(size_t)(cr) * DK + cs];
    uint4 kB = *(const uint4*)&kbase[(size_t)(cr + 32) * DK + cs];
    uint4 vA = *(const uint4*)&vbase[(size_t)cr * S_LEN + cs];
    uint4 vB = *(const uint4*)&vbase[(size_t)(cr + 32) * S_LEN + cs];

    for (int kt = 0; kt < S_LEN / 64; ++kt) {
        __syncthreads();              // previous tile's LDS reads done
        *(uint4*)&Ks[cr][cs]      = kA;
        *(uint4*)&Ks[cr + 32][cs] = kB;
        *(uint4*)&Vs[cr][cs]      = vA;
        *(uint4*)&Vs[cr + 32][cs] = vB;
        if (kt + 1 < S_LEN / 64) {    // async prefetch next tile into regs
            const int o = (kt + 1) * 64;
            kA = *(const uint4*)&kbase[(size_t)(o + cr) * DK + cs];
            kB = *(const uint4*)&kbase[(size_t)(o + cr + 32) * DK + cs];
            vA = *(const uint4*)&vbase[(size_t)cr * S_LEN + o + cs];
            vB = *(const uint4*)&vbase[(size_t)(cr + 32) * S_LEN + o + cs];
        }
        __syncthreads();

        // swapped QK^T: sc[nt][r] = S'[key=nt*16+g*4+r][q=c] (log2 units)
        f32x4 sc[4] = {};
        __builtin_amdgcn_s_setprio(1);
#pragma unroll
        for (int nt = 0; nt < 4; ++nt) {
            const f16x8 ka = *(const f16x8*)&Ks[nt * 16 + c][g * 8];
            const f16x8 kb = *(const f16x8*)&Ks[nt * 16 + c][32 + g * 8];
            sc[nt] = __builtin_amdgcn_mfma_f32_16x16x32_f16(ka, bQ0, sc[nt], 0, 0, 0);
            sc[nt] = __builtin_amdgcn_mfma_f32_16x16x32_f16(kb, bQ1, sc[nt], 0, 0, 0);
        }
        __builtin_amdgcn_s_setprio(0);

        // softmax for q=c: lane-local 16 keys + 2 cross-group shfls
        float tmax = sc[0][0];
#pragma unroll
        for (int nt = 0; nt < 4; ++nt)
#pragma unroll
            for (int r = 0; r < 4; ++r) tmax = fmaxf(tmax, sc[nt][r]);
        tmax = fmaxf(tmax, __shfl_xor(tmax, 16));
        tmax = fmaxf(tmax, __shfl_xor(tmax, 32));

        // defer-max (T13): only rescale when some row's max grew by >8 (2^8 bound)
        if (!__all(tmax <= m_run + 8.f)) {
            const float mnew = fmaxf(m_run, tmax);
            const float fac = exp2_fast(m_run - mnew);   // 0 on first tile
            m_run = mnew;
            l_run *= fac;
#pragma unroll
            for (int r = 0; r < 4; ++r) {
                const float fr = __shfl(fac, (lane & 48) + ((lane >> 4) & 3) * 4 + r);
                oa[0][r] *= fr; oa[1][r] *= fr; oa[2][r] *= fr; oa[3][r] *= fr;
            }
        }

        float e[4][4];
        float tsum = 0.f;
#pragma unroll
        for (int nt = 0; nt < 4; ++nt)
#pragma unroll
            for (int r = 0; r < 4; ++r) {
                e[nt][r] = exp2_fast(sc[nt][r] - m_run);
                tsum += e[nt][r];
            }
        tsum += __shfl_xor(tsum, 16);
        tsum += __shfl_xor(tsum, 32);
        l_run += tsum;

        // PV: A-fragment = lane's own exp values (key order pi = perm6 inverse)
        const f16x8 aP0 = {(f16)e[0][0], (f16)e[0][1], (f16)e[0][2], (f16)e[0][3],
                           (f16)e[1][0], (f16)e[1][1], (f16)e[1][2], (f16)e[1][3]};
        const f16x8 aP1 = {(f16)e[2][0], (f16)e[2][1], (f16)e[2][2], (f16)e[2][3],
                           (f16)e[3][0], (f16)e[3][1], (f16)e[3][2], (f16)e[3][3]};

        __builtin_amdgcn_s_setprio(1);
#pragma unroll
        for (int nt2 = 0; nt2 < 4; ++nt2) {
            const f16x8 b0 = *(const f16x8*)&Vs[nt2 * 16 + c][g * 8];        // keys' 0..31
            const f16x8 b1 = *(const f16x8*)&Vs[nt2 * 16 + c][32 + g * 8];   // keys' 32..63
            oa[nt2] = __builtin_amdgcn_mfma_f32_16x16x32_f16(aP0, b0, oa[nt2], 0, 0, 0);
            oa[nt2] = __builtin_amdgcn_mfma_f32_16x16x32_f16(aP1, b1, oa[nt2], 0, 0, 0);
        }
        __builtin_amdgcn_s_setprio(0);
    }

    // epilogue
    const float invc = 1.f / l_run;
#pragma unroll
    for (int r = 0; r < 4; ++r) {
        const float ir = __shfl(invc, (lane & 48) + ((lane >> 4) & 3) * 4 + r);
        const int srow = qrow0 + ((lane >> 4) & 3) * 4 + r;
#pragma unroll
        for (int nt2 = 0; nt2 < 4; ++nt2) {
            ao[((size_t)b * S_LEN + srow) * D_MODEL + h * DK + nt2 * 16 + c] = (f16)(oa[nt2][r] * ir);
        }
    }
}

// ---------------------------------------------------------------------------
extern "C" void kernel_launch(void* const* d_in, const int* in_sizes, int n_in,
                              void* d_out, int out_size, void* d_ws, size_t ws_size,
                              hipStream_t stream) {
    const float* Q  = (const float*)d_in[0];
    const float* K  = (const float*)d_in[1];
    const float* V  = (const float*)d_in[2];
    const float* Wq = (const float*)d_in[3];
    const float* bq = (const float*)d_in[4];
    const float* Wk = (const float*)d_in[5];
    const float* bk = (const float*)d_in[6];
    const float* Wv = (const float*)d_in[7];
    const float* bv = (const float*)d_in[8];
    const float* Wo = (const float*)d_in[9];
    const float* bo = (const float*)d_in[10];
    float* out = (float*)d_out;

    const size_t NELEM = (size_t)M_ROWS * D_MODEL;   // 4M
    const size_t WELEM = (size_t)D_MODEL * D_MODEL;  // 1M
    f16* Qf  = (f16*)d_ws;
    f16* Kf  = Qf + NELEM;
    f16* Vf  = Kf + NELEM;
    f16* Wqf = Vf + NELEM;
    f16* Wkf = Wqf + WELEM;
    f16* Wvf = Wkf + WELEM;
    f16* Wof = Wvf + WELEM;
    f16* qh  = Wof + WELEM;   // [bh][s][dk], pre-scaled by 0.125*log2e
    f16* kh  = qh + NELEM;    // [bh][s][dk]
    f16* vtw = kh + NELEM;    // [bh][dk][s'] (perm6 key order)
    f16* aow = vtw + NELEM;   // [b][s][d_model] f16

    cvt_f32_to_f16<<<dim3(2048, 3), 256, 0, stream>>>(Q, K, V, nullptr, Qf, Kf, Vf, nullptr,
                                                      (int)(NELEM / 8));
    cvt_f32_to_f16<<<dim3(512, 4), 256, 0, stream>>>(Wq, Wk, Wv, Wo, Wqf, Wkf, Wvf, Wof,
                                                     (int)(WELEM / 8));
    qkv_gemm<<<dim3(D_MODEL / 128, M_ROWS / 128, 3), 256, 0, stream>>>(
        Qf, Kf, Vf, Wqf, Wkf, Wvf, bq, bk, bv, qh, kh, vtw);
    flash_mfma<<<dim3(S_LEN / 64, BATCH * NH), 256, 0, stream>>>(qh, kh, vtw, aow);
    out_gemm<<<dim3(D_MODEL / 128, M_ROWS / 64), 256, 0, stream>>>(aow, Wof, bo, out);
}